// Round 4
// baseline (340.210 us; speedup 1.0000x reference)
//
#include <hip/hip_runtime.h>

typedef __bf16 bf16;
typedef __bf16 bf16x8 __attribute__((ext_vector_type(8)));
typedef float f32x4 __attribute__((ext_vector_type(4)));

#define MFMA16(a,b,c) __builtin_amdgcn_mfma_f32_16x16x32_bf16((a),(b),(c),0,0,0)

// Shapes (fixed): B=32, N=384, C=768, H=12, Dh=64, mt=128, 2B=64 batches.
// Global inputs/outputs FLOAT32; intermediates bf16.
// Xb (x bf16 [24576][768]) + Wq (qkv_w bf16 [2304][768]) live in d_out scratch.
// ws: Q | K | V | ATT (each 36 MB bf16) = 151 MB; Wp reuses Q after attn.
//
// GEMMs: 2-phase double-buffered LDS pipeline (prefetch K-tile t+1 while
// computing t; ONE barrier per K-step) + XOR bank swizzle (slot ^= (row>>1)&3,
// pre-swizzled global source because global_load_lds writes linearly).

__device__ inline void gload16(const bf16* g, bf16* l) {
  __builtin_amdgcn_global_load_lds(
      (const __attribute__((address_space(1))) void*)g,
      (__attribute__((address_space(3))) void*)l, 16, 0, 0);
}

// Stage one 128x32 A-tile + 128x32 B-tile (bf16) with swizzled source cols.
// LDS layout: row-major [128][32], row = slot>>2, 16B-slot = slot&3, where the
// data stored at slot s is global column chunk ((s&3) ^ ((s>>3)&3)).
__device__ inline void stage_pair(const bf16* __restrict__ Xp,
                                  const bf16* __restrict__ Wp,
                                  bf16* Ab, bf16* Bb, int tid, int wv) {
#pragma unroll
  for (int i = 0; i < 2; ++i) {
    int s = i * 256 + tid;                       // 0..511
    int row = s >> 2;
    int c8 = (((s & 3) ^ ((s >> 3) & 3))) * 8;   // swizzled col (elems)
    bf16* la = Ab + (size_t)(i * 256 + wv * 64) * 8;
    gload16(Xp + (size_t)row * 768 + c8, la);
    bf16* lb = Bb + (size_t)(i * 256 + wv * 64) * 8;
    gload16(Wp + (size_t)row * 768 + c8, lb);
  }
}

// ---------------------------------------------------------------------------
// convert1: pack xv | xi | qkv_w (f32) -> bf16 into d_out scratch.
// ---------------------------------------------------------------------------
__global__ __launch_bounds__(256) void convert1_kernel(
    const float* __restrict__ xv, const float* __restrict__ xi,
    const float* __restrict__ w, bf16* __restrict__ dst)
{
  const size_t NV = 9437184;     // 12288*768
  const size_t NX = 18874368;    // 2*NV
  const size_t NT = 20643840;    // NX + 1769472 (qkv_w)
  for (size_t i = (size_t)blockIdx.x * 256 + threadIdx.x; i * 8 < NT;
       i += (size_t)gridDim.x * 256) {
    size_t e = i * 8;
    const float* src;
    if (e < NV)      src = xv + e;
    else if (e < NX) src = xi + (e - NV);
    else             src = w + (e - NX);
    f32x4 a = *(const f32x4*)src;
    f32x4 b = *(const f32x4*)(src + 4);
    bf16x8 r;
    r[0] = (bf16)a[0]; r[1] = (bf16)a[1]; r[2] = (bf16)a[2]; r[3] = (bf16)a[3];
    r[4] = (bf16)b[0]; r[5] = (bf16)b[1]; r[6] = (bf16)b[2]; r[7] = (bf16)b[3];
    *(bf16x8*)(dst + e) = r;
  }
}

// convert2: proj_w (f32, 589824) -> bf16 (into dead Q region).
__global__ __launch_bounds__(256) void convert2_kernel(
    const float* __restrict__ w, bf16* __restrict__ dst)
{
  size_t i = (size_t)blockIdx.x * 256 + threadIdx.x;
  size_t e = i * 8;
  if (e >= 589824) return;
  f32x4 a = *(const f32x4*)(w + e);
  f32x4 b = *(const f32x4*)(w + e + 4);
  bf16x8 r;
  r[0] = (bf16)a[0]; r[1] = (bf16)a[1]; r[2] = (bf16)a[2]; r[3] = (bf16)a[3];
  r[4] = (bf16)b[0]; r[5] = (bf16)b[1]; r[6] = (bf16)b[2]; r[7] = (bf16)b[3];
  *(bf16x8*)(dst + e) = r;
}

// ---------------------------------------------------------------------------
// Kernel 1: QKV projection, 2-phase pipelined, swizzled LDS.
// 128x128 tile, BK=32, 4 waves each 64x64. Scatter epilogue into Q/K/V.
// ---------------------------------------------------------------------------
__global__ __launch_bounds__(256) void qkv_kernel(
    const bf16* __restrict__ X, const bf16* __restrict__ W,
    bf16* __restrict__ Qo, bf16* __restrict__ Ko, bf16* __restrict__ Vo)
{
  __shared__ bf16 As[2][128][32];
  __shared__ bf16 Bs[2][128][32];
  int bid = blockIdx.x;                    // 3456 blocks
  int swz = (bid & 7) * 432 + (bid >> 3);  // XCD-contiguous, bijective
  const int nt = swz % 18, mt = swz / 18;
  const int m0 = mt * 128, n0 = nt * 128;
  const int tid = threadIdx.x;
  const int lane = tid & 63;
  const int wv = tid >> 6;
  const int wr = (wv >> 1) * 64, wc = (wv & 1) * 64;
  const int lr = lane & 15, lg = lane >> 4;
  const int xb = (lg ^ ((lr >> 1) & 3)) * 16;   // swizzled byte offset in row

  const bf16* Xp = X + (size_t)m0 * 768;
  const bf16* Wp = W + (size_t)n0 * 768;

  f32x4 acc[4][4] = {};

  stage_pair(Xp, Wp, &As[0][0][0], &Bs[0][0][0], tid, wv);
  __syncthreads();

  int cur = 0;
  for (int kt = 0; kt < 768; kt += 32) {
    if (kt + 32 < 768)
      stage_pair(Xp + kt + 32, Wp + kt + 32,
                 &As[cur ^ 1][0][0], &Bs[cur ^ 1][0][0], tid, wv);
    const bf16* Ac = &As[cur][0][0];
    const bf16* Bc = &Bs[cur][0][0];
    bf16x8 af[4], bfr[4];
#pragma unroll
    for (int mf = 0; mf < 4; ++mf)
      af[mf] = *(const bf16x8*)((const char*)(Ac + (size_t)(wr + mf * 16 + lr) * 32) + xb);
#pragma unroll
    for (int nf = 0; nf < 4; ++nf)
      bfr[nf] = *(const bf16x8*)((const char*)(Bc + (size_t)(wc + nf * 16 + lr) * 32) + xb);
#pragma unroll
    for (int mf = 0; mf < 4; ++mf)
#pragma unroll
      for (int nf = 0; nf < 4; ++nf)
        acc[mf][nf] = MFMA16(af[mf], bfr[nf], acc[mf][nf]);
    __syncthreads();      // drains vmcnt (prefetch) + lgkm; buffers swap-safe
    cur ^= 1;
  }

#pragma unroll
  for (int mf = 0; mf < 4; ++mf)
#pragma unroll
    for (int nf = 0; nf < 4; ++nf)
#pragma unroll
      for (int r = 0; r < 4; ++r) {
        int m = m0 + wr + mf * 16 + lg * 4 + r;
        int n = n0 + wc + nf * 16 + lr;
        int bp = m / 384, tok = m - bp * 384;
        int comp = (n >= 1536) ? 2 : (n >= 768) ? 1 : 0;
        int rem = n - comp * 768;
        int hh = rem >> 6, d = rem & 63;
        size_t addr = (((size_t)bp * 12 + hh) * 384 + tok) * 64 + d;
        float val = acc[mf][nf][r];
        if (comp == 0)      Qo[addr] = (bf16)(val * 0.125f);   // fold 1/sqrt(Dh)
        else if (comp == 1) Ko[addr] = (bf16)val;
        else                Vo[addr] = (bf16)val;
      }
}

// ---------------------------------------------------------------------------
// Kernel 2: attention (unchanged). grid = 64*12*3.
// ---------------------------------------------------------------------------
__global__ __launch_bounds__(256) void attn_kernel(
    const bf16* __restrict__ Q, const bf16* __restrict__ K, const bf16* __restrict__ V,
    bf16* __restrict__ ATT)
{
  __shared__ union {
    bf16 Qs[128][72];
    bf16 Ps[4][32][136];     // per-wave P tile (Qs dead after qf reg-cache)
  } u;
  __shared__ bf16 Ks[128][72];
  __shared__ bf16 VTs[64][136];     // transposed V: [d][token]

  const int bid = blockIdx.x;
  const int qb = bid % 3;
  const int h  = (bid / 3) % 12;
  const int bp = bid / 36;           // b' in [0,64)
  const int tid = threadIdx.x;
  const int lane = tid & 63;
  const int wv = tid >> 6;
  const int lr = lane & 15, lg = lane >> 4;

  const size_t bh384 = ((size_t)bp * 12 + h) * 384;
  const int q0 = qb * 128;

  for (int v = tid; v < 1024; v += 256) {
    int row = v >> 3, cg = (v & 7) * 8;
    *(bf16x8*)(&u.Qs[row][cg]) = *(const bf16x8*)(Q + (bh384 + q0 + row) * 64 + cg);
  }
  __syncthreads();

  bf16x8 qf[2][2];
#pragma unroll
  for (int mf = 0; mf < 2; ++mf)
#pragma unroll
    for (int ks = 0; ks < 2; ++ks)
      qf[mf][ks] = *(const bf16x8*)(&u.Qs[wv * 32 + mf * 16 + lr][ks * 32 + lg * 8]);

  f32x4 O[2][4] = {};
  float runmax[2][4], runsum[2][4];
#pragma unroll
  for (int mf = 0; mf < 2; ++mf)
#pragma unroll
    for (int r = 0; r < 4; ++r) { runmax[mf][r] = -1e30f; runsum[mf][r] = 0.f; }

  const int nchunks = (qb == 0) ? 1 : 4;
  for (int c = 0; c < nchunks; ++c) {
    int src_b, t0;
    if (qb == 0)      { src_b = bp;            t0 = 0; }
    else if (c == 0)  { src_b = bp & 31;       t0 = 0; }          // mt of V batch
    else if (c == 1)  { src_b = (bp & 31)+32;  t0 = 0; }          // mt of I batch
    else              { src_b = bp;            t0 = (c - 1) * 128; } // own s tokens
    const size_t kb = (((size_t)src_b * 12 + h) * 384 + t0) * 64;

    __syncthreads();   // previous chunk fully consumed before restaging
    for (int v = tid; v < 1024; v += 256) {
      int row = v >> 3, cg = (v & 7) * 8;
      *(bf16x8*)(&Ks[row][cg]) = *(const bf16x8*)(K + kb + row * 64 + cg);
      bf16x8 vvld = *(const bf16x8*)(V + kb + row * 64 + cg);
#pragma unroll
      for (int j = 0; j < 8; ++j) VTs[cg + j][row] = vvld[j];
    }
    __syncthreads();

    // S = Q * Kc^T   (scale already folded into Q)
    f32x4 S[2][8] = {};
#pragma unroll
    for (int nf = 0; nf < 8; ++nf) {
#pragma unroll
      for (int ks = 0; ks < 2; ++ks) {
        bf16x8 kf = *(const bf16x8*)(&Ks[nf * 16 + lr][ks * 32 + lg * 8]);
        S[0][nf] = MFMA16(qf[0][ks], kf, S[0][nf]);
        S[1][nf] = MFMA16(qf[1][ks], kf, S[1][nf]);
      }
    }

    // online softmax (row = lg*4 + r within 16-row fragment; 16-lane reduce)
#pragma unroll
    for (int mf = 0; mf < 2; ++mf) {
#pragma unroll
      for (int r = 0; r < 4; ++r) {
        float mx = S[mf][0][r];
#pragma unroll
        for (int nf = 1; nf < 8; ++nf) mx = fmaxf(mx, S[mf][nf][r]);
        mx = fmaxf(mx, __shfl_xor(mx, 1));
        mx = fmaxf(mx, __shfl_xor(mx, 2));
        mx = fmaxf(mx, __shfl_xor(mx, 4));
        mx = fmaxf(mx, __shfl_xor(mx, 8));
        float nm = fmaxf(runmax[mf][r], mx);
        float rf = __expf(runmax[mf][r] - nm);
        float rs = 0.f;
#pragma unroll
        for (int nf = 0; nf < 8; ++nf) {
          float p = __expf(S[mf][nf][r] - nm);
          S[mf][nf][r] = p;
          rs += p;
        }
        rs += __shfl_xor(rs, 1);
        rs += __shfl_xor(rs, 2);
        rs += __shfl_xor(rs, 4);
        rs += __shfl_xor(rs, 8);
        runsum[mf][r] = runsum[mf][r] * rf + rs;
        runmax[mf][r] = nm;
#pragma unroll
        for (int vn = 0; vn < 4; ++vn) O[mf][vn][r] *= rf;
      }
    }

    // P (C-layout) -> LDS -> A-layout fragments.  Wave-private; DS in-order.
#pragma unroll
    for (int mf = 0; mf < 2; ++mf)
#pragma unroll
      for (int nf = 0; nf < 8; ++nf)
#pragma unroll
        for (int r = 0; r < 4; ++r)
          u.Ps[wv][mf * 16 + lg * 4 + r][nf * 16 + lr] = (bf16)S[mf][nf][r];

#pragma unroll
    for (int ks = 0; ks < 4; ++ks) {
      bf16x8 pf0 = *(const bf16x8*)(&u.Ps[wv][lr][ks * 32 + lg * 8]);
      bf16x8 pf1 = *(const bf16x8*)(&u.Ps[wv][16 + lr][ks * 32 + lg * 8]);
#pragma unroll
      for (int vn = 0; vn < 4; ++vn) {
        bf16x8 vf = *(const bf16x8*)(&VTs[vn * 16 + lr][ks * 32 + lg * 8]);
        O[0][vn] = MFMA16(pf0, vf, O[0][vn]);
        O[1][vn] = MFMA16(pf1, vf, O[1][vn]);
      }
    }
  }

#pragma unroll
  for (int mf = 0; mf < 2; ++mf)
#pragma unroll
    for (int vn = 0; vn < 4; ++vn)
#pragma unroll
      for (int r = 0; r < 4; ++r) {
        int tok = q0 + wv * 32 + mf * 16 + lg * 4 + r;
        int d = vn * 16 + lr;
        float o = O[mf][vn][r] / runsum[mf][r];
        ATT[((size_t)bp * 384 + tok) * 768 + h * 64 + d] = (bf16)o;
      }
}

// ---------------------------------------------------------------------------
// Kernel 3: output projection, 2-phase pipelined, swizzled LDS, f32 out+bias.
// ---------------------------------------------------------------------------
__global__ __launch_bounds__(256) void proj_kernel(
    const bf16* __restrict__ A, const bf16* __restrict__ W,
    const float* __restrict__ bias, float* __restrict__ out)
{
  __shared__ bf16 As[2][128][32];
  __shared__ bf16 Bs[2][128][32];
  int bid = blockIdx.x;                    // 1152 blocks
  int swz = (bid & 7) * 144 + (bid >> 3);
  const int nt = swz % 6, mt = swz / 6;
  const int m0 = mt * 128, n0 = nt * 128;
  const int tid = threadIdx.x;
  const int lane = tid & 63;
  const int wv = tid >> 6;
  const int wr = (wv >> 1) * 64, wc = (wv & 1) * 64;
  const int lr = lane & 15, lg = lane >> 4;
  const int xb = (lg ^ ((lr >> 1) & 3)) * 16;

  const bf16* Ap = A + (size_t)m0 * 768;
  const bf16* Wp = W + (size_t)n0 * 768;

  f32x4 acc[4][4] = {};

  stage_pair(Ap, Wp, &As[0][0][0], &Bs[0][0][0], tid, wv);
  __syncthreads();

  int cur = 0;
  for (int kt = 0; kt < 768; kt += 32) {
    if (kt + 32 < 768)
      stage_pair(Ap + kt + 32, Wp + kt + 32,
                 &As[cur ^ 1][0][0], &Bs[cur ^ 1][0][0], tid, wv);
    const bf16* Ac = &As[cur][0][0];
    const bf16* Bc = &Bs[cur][0][0];
    bf16x8 af[4], bfr[4];
#pragma unroll
    for (int mf = 0; mf < 4; ++mf)
      af[mf] = *(const bf16x8*)((const char*)(Ac + (size_t)(wr + mf * 16 + lr) * 32) + xb);
#pragma unroll
    for (int nf = 0; nf < 4; ++nf)
      bfr[nf] = *(const bf16x8*)((const char*)(Bc + (size_t)(wc + nf * 16 + lr) * 32) + xb);
#pragma unroll
    for (int mf = 0; mf < 4; ++mf)
#pragma unroll
      for (int nf = 0; nf < 4; ++nf)
        acc[mf][nf] = MFMA16(af[mf], bfr[nf], acc[mf][nf]);
    __syncthreads();
    cur ^= 1;
  }

#pragma unroll
  for (int mf = 0; mf < 4; ++mf)
#pragma unroll
    for (int nf = 0; nf < 4; ++nf)
#pragma unroll
      for (int r = 0; r < 4; ++r) {
        int m = m0 + wr + mf * 16 + lg * 4 + r;
        int n = n0 + wc + nf * 16 + lr;
        out[(size_t)m * 768 + n] = acc[mf][nf][r] + bias[n];
      }
}

// ---------------------------------------------------------------------------
extern "C" void kernel_launch(void* const* d_in, const int* in_sizes, int n_in,
                              void* d_out, int out_size, void* d_ws, size_t ws_size,
                              hipStream_t stream) {
  (void)in_sizes; (void)n_in; (void)out_size; (void)ws_size;
  const float* xv     = (const float*)d_in[0];
  const float* xi     = (const float*)d_in[1];
  const float* qkv_w  = (const float*)d_in[2];
  const float* proj_w = (const float*)d_in[3];
  const float* proj_b = (const float*)d_in[4];
  float* out = (float*)d_out;

  // bf16 scratch inside d_out (75.5 MB): Xb [24576][768] then Wq [2304][768].
  bf16* Xb = (bf16*)d_out;
  bf16* Wq = Xb + (size_t)18874368;

  // ws: Q | K | V | ATT, each 18874368 bf16 (~36 MB) = 151 MB total.
  const size_t SZ = (size_t)64 * 12 * 384 * 64;
  bf16* Q   = (bf16*)d_ws;
  bf16* K   = Q + SZ;
  bf16* V   = K + SZ;
  bf16* ATT = V + SZ;
  bf16* Wp  = Q;                 // proj_w bf16, reuses Q region after attn

  convert1_kernel<<<2048, 256, 0, stream>>>(xv, xi, qkv_w, Xb);
  qkv_kernel<<<3456, 256, 0, stream>>>(Xb, Wq, Q, K, V);
  attn_kernel<<<64 * 12 * 3, 256, 0, stream>>>(Q, K, V, ATT);
  convert2_kernel<<<288, 256, 0, stream>>>(proj_w, Wp);
  proj_kernel<<<1152, 256, 0, stream>>>(ATT, Wp, proj_b, out);
}

// Round 5
// 316.629 us; speedup vs baseline: 1.0745x; 1.0745x over previous
//
#include <hip/hip_runtime.h>

typedef __bf16 bf16;
typedef __bf16 bf16x8 __attribute__((ext_vector_type(8)));
typedef float f32x4 __attribute__((ext_vector_type(4)));

#define MFMA16(a,b,c) __builtin_amdgcn_mfma_f32_16x16x32_bf16((a),(b),(c),0,0,0)

// Shapes (fixed): B=32, N=384, C=768, H=12, Dh=64, mt=128, 2B=64 batches.
// Global inputs/outputs FLOAT32; intermediates bf16.
// Xb (x bf16 [24576][768]) + Wq (qkv_w bf16 [2304][768]) live in d_out scratch.
// ws: Q | K | V | ATT (each 36 MB bf16) = 151 MB; Wp reuses Q after attn.
//
// GEMMs: 256x256 tile, BK=64, 8 waves (512 thr), per-wave 128x64 output.
// Double-buffered LDS (128 KB), prefetch next K-tile at loop top, ONE
// __syncthreads per K-step (verified skeleton from r3/r4, scaled 4x so the
// ~64-MFMA/wave compute covers the prefetch latency the barrier drains).
// 8-slot XOR swizzle (slot ^= row&7) on BOTH store-source and read.

__device__ inline void gload16(const bf16* g, bf16* l) {
  __builtin_amdgcn_global_load_lds(
      (const __attribute__((address_space(1))) void*)g,
      (__attribute__((address_space(3))) void*)l, 16, 0, 0);
}

// Stage one 256x64 bf16 tile (32 KB) from row-major [*,768] global panel.
// LDS linear dest; global column chunk pre-swizzled: chunk = (s&7)^(row&7).
__device__ inline void stage_tile64(const bf16* __restrict__ gsrc,
                                    bf16* lds_base, int tid, int wv) {
#pragma unroll
  for (int r = 0; r < 4; ++r) {
    int s = r * 512 + tid;                        // 0..2047
    int row = s >> 3;
    int chunk = (s & 7) ^ (row & 7);
    bf16* l = lds_base + (size_t)(r * 512 + wv * 64) * 8;   // 16B per lane
    gload16(gsrc + (size_t)row * 768 + chunk * 8, l);
  }
}

// Read a 16B MFMA fragment at (row, ksub, lg) from a swizzled 256x64 tile.
__device__ inline bf16x8 frag64(const bf16* buf, int row, int ks, int lg) {
  int slot = ((ks << 2) | lg) ^ (row & 7);
  return *(const bf16x8*)(buf + (size_t)row * 64 + slot * 8);
}

// ---------------------------------------------------------------------------
// convert1: pack xv | xi | qkv_w (f32) -> bf16 into d_out scratch.
// ---------------------------------------------------------------------------
__global__ __launch_bounds__(256) void convert1_kernel(
    const float* __restrict__ xv, const float* __restrict__ xi,
    const float* __restrict__ w, bf16* __restrict__ dst)
{
  const size_t NV = 9437184;     // 12288*768
  const size_t NX = 18874368;    // 2*NV
  const size_t NT = 20643840;    // NX + 1769472 (qkv_w)
  for (size_t i = (size_t)blockIdx.x * 256 + threadIdx.x; i * 8 < NT;
       i += (size_t)gridDim.x * 256) {
    size_t e = i * 8;
    const float* src;
    if (e < NV)      src = xv + e;
    else if (e < NX) src = xi + (e - NV);
    else             src = w + (e - NX);
    f32x4 a = *(const f32x4*)src;
    f32x4 b = *(const f32x4*)(src + 4);
    bf16x8 r;
    r[0] = (bf16)a[0]; r[1] = (bf16)a[1]; r[2] = (bf16)a[2]; r[3] = (bf16)a[3];
    r[4] = (bf16)b[0]; r[5] = (bf16)b[1]; r[6] = (bf16)b[2]; r[7] = (bf16)b[3];
    *(bf16x8*)(dst + e) = r;
  }
}

// convert2: proj_w (f32, 589824) -> bf16 (into dead Q region).
__global__ __launch_bounds__(256) void convert2_kernel(
    const float* __restrict__ w, bf16* __restrict__ dst)
{
  size_t i = (size_t)blockIdx.x * 256 + threadIdx.x;
  size_t e = i * 8;
  if (e >= 589824) return;
  f32x4 a = *(const f32x4*)(w + e);
  f32x4 b = *(const f32x4*)(w + e + 4);
  bf16x8 r;
  r[0] = (bf16)a[0]; r[1] = (bf16)a[1]; r[2] = (bf16)a[2]; r[3] = (bf16)a[3];
  r[4] = (bf16)b[0]; r[5] = (bf16)b[1]; r[6] = (bf16)b[2]; r[7] = (bf16)b[3];
  *(bf16x8*)(dst + e) = r;
}

// ---------------------------------------------------------------------------
// Kernel 1: QKV projection. 256x256 tile, BK=64, scatter epilogue to Q/K/V.
// ---------------------------------------------------------------------------
__global__ __launch_bounds__(512, 2) void qkv_kernel(
    const bf16* __restrict__ X, const bf16* __restrict__ W,
    bf16* __restrict__ Qo, bf16* __restrict__ Ko, bf16* __restrict__ Vo)
{
  __shared__ bf16 As[2][256][64];
  __shared__ bf16 Bs[2][256][64];
  int bid = blockIdx.x;                    // 864 blocks
  int swz = (bid & 7) * 108 + (bid >> 3);  // XCD-contiguous, bijective (864=8*108)
  const int nt = swz % 9, mt = swz / 9;    // n fastest: A-panel reuse in XCD
  const int m0 = mt * 256, n0 = nt * 256;
  const int tid = threadIdx.x;
  const int lane = tid & 63;
  const int wv = tid >> 6;                 // 0..7
  const int wm = wv >> 2, wn = wv & 3;     // 2x4 wave grid; wave out 128x64
  const int lr = lane & 15, lg = lane >> 4;

  const bf16* Xp = X + (size_t)m0 * 768;
  const bf16* Wp = W + (size_t)n0 * 768;

  f32x4 acc[8][4] = {};

  stage_tile64(Xp, &As[0][0][0], tid, wv);
  stage_tile64(Wp, &Bs[0][0][0], tid, wv);
  __syncthreads();

  for (int t = 0; t < 12; ++t) {
    if (t + 1 < 12) {
      stage_tile64(Xp + (t + 1) * 64, &As[(t + 1) & 1][0][0], tid, wv);
      stage_tile64(Wp + (t + 1) * 64, &Bs[(t + 1) & 1][0][0], tid, wv);
    }
    const bf16* Ab = &As[t & 1][0][0];
    const bf16* Bb = &Bs[t & 1][0][0];
    bf16x8 bfrag[4][2];
#pragma unroll
    for (int nf = 0; nf < 4; ++nf)
#pragma unroll
      for (int ks = 0; ks < 2; ++ks)
        bfrag[nf][ks] = frag64(Bb, wn * 64 + nf * 16 + lr, ks, lg);
#pragma unroll
    for (int mq = 0; mq < 4; ++mq) {
      bf16x8 af[2][2];
#pragma unroll
      for (int i = 0; i < 2; ++i)
#pragma unroll
        for (int ks = 0; ks < 2; ++ks)
          af[i][ks] = frag64(Ab, wm * 128 + (mq * 2 + i) * 16 + lr, ks, lg);
#pragma unroll
      for (int i = 0; i < 2; ++i)
#pragma unroll
        for (int nf = 0; nf < 4; ++nf)
#pragma unroll
          for (int ks = 0; ks < 2; ++ks)
            acc[mq * 2 + i][nf] = MFMA16(af[i][ks], bfrag[nf][ks], acc[mq * 2 + i][nf]);
    }
    __syncthreads();   // drains vmcnt (t+1 prefetch) + lgkm; swap-safe
  }

#pragma unroll
  for (int mf = 0; mf < 8; ++mf)
#pragma unroll
    for (int nf = 0; nf < 4; ++nf)
#pragma unroll
      for (int r = 0; r < 4; ++r) {
        int m = m0 + wm * 128 + mf * 16 + lg * 4 + r;
        int n = n0 + wn * 64 + nf * 16 + lr;
        int bp = m / 384, tok = m - bp * 384;
        int comp = (n >= 1536) ? 2 : (n >= 768) ? 1 : 0;
        int rem = n - comp * 768;
        int hh = rem >> 6, d = rem & 63;
        size_t addr = (((size_t)bp * 12 + hh) * 384 + tok) * 64 + d;
        float val = acc[mf][nf][r];
        if (comp == 0)      Qo[addr] = (bf16)(val * 0.125f);   // fold 1/sqrt(Dh)
        else if (comp == 1) Ko[addr] = (bf16)val;
        else                Vo[addr] = (bf16)val;
      }
}

// ---------------------------------------------------------------------------
// Kernel 2: attention (unchanged, verified). grid = 64*12*3.
// ---------------------------------------------------------------------------
__global__ __launch_bounds__(256) void attn_kernel(
    const bf16* __restrict__ Q, const bf16* __restrict__ K, const bf16* __restrict__ V,
    bf16* __restrict__ ATT)
{
  __shared__ union {
    bf16 Qs[128][72];
    bf16 Ps[4][32][136];     // per-wave P tile (Qs dead after qf reg-cache)
  } u;
  __shared__ bf16 Ks[128][72];
  __shared__ bf16 VTs[64][136];     // transposed V: [d][token]

  const int bid = blockIdx.x;
  const int qb = bid % 3;
  const int h  = (bid / 3) % 12;
  const int bp = bid / 36;           // b' in [0,64)
  const int tid = threadIdx.x;
  const int lane = tid & 63;
  const int wv = tid >> 6;
  const int lr = lane & 15, lg = lane >> 4;

  const size_t bh384 = ((size_t)bp * 12 + h) * 384;
  const int q0 = qb * 128;

  for (int v = tid; v < 1024; v += 256) {
    int row = v >> 3, cg = (v & 7) * 8;
    *(bf16x8*)(&u.Qs[row][cg]) = *(const bf16x8*)(Q + (bh384 + q0 + row) * 64 + cg);
  }
  __syncthreads();

  bf16x8 qf[2][2];
#pragma unroll
  for (int mf = 0; mf < 2; ++mf)
#pragma unroll
    for (int ks = 0; ks < 2; ++ks)
      qf[mf][ks] = *(const bf16x8*)(&u.Qs[wv * 32 + mf * 16 + lr][ks * 32 + lg * 8]);

  f32x4 O[2][4] = {};
  float runmax[2][4], runsum[2][4];
#pragma unroll
  for (int mf = 0; mf < 2; ++mf)
#pragma unroll
    for (int r = 0; r < 4; ++r) { runmax[mf][r] = -1e30f; runsum[mf][r] = 0.f; }

  const int nchunks = (qb == 0) ? 1 : 4;
  for (int c = 0; c < nchunks; ++c) {
    int src_b, t0;
    if (qb == 0)      { src_b = bp;            t0 = 0; }
    else if (c == 0)  { src_b = bp & 31;       t0 = 0; }          // mt of V batch
    else if (c == 1)  { src_b = (bp & 31)+32;  t0 = 0; }          // mt of I batch
    else              { src_b = bp;            t0 = (c - 1) * 128; } // own s tokens
    const size_t kb = (((size_t)src_b * 12 + h) * 384 + t0) * 64;

    __syncthreads();   // previous chunk fully consumed before restaging
    for (int v = tid; v < 1024; v += 256) {
      int row = v >> 3, cg = (v & 7) * 8;
      *(bf16x8*)(&Ks[row][cg]) = *(const bf16x8*)(K + kb + row * 64 + cg);
      bf16x8 vvld = *(const bf16x8*)(V + kb + row * 64 + cg);
#pragma unroll
      for (int j = 0; j < 8; ++j) VTs[cg + j][row] = vvld[j];
    }
    __syncthreads();

    // S = Q * Kc^T   (scale already folded into Q)
    f32x4 S[2][8] = {};
#pragma unroll
    for (int nf = 0; nf < 8; ++nf) {
#pragma unroll
      for (int ks = 0; ks < 2; ++ks) {
        bf16x8 kf = *(const bf16x8*)(&Ks[nf * 16 + lr][ks * 32 + lg * 8]);
        S[0][nf] = MFMA16(qf[0][ks], kf, S[0][nf]);
        S[1][nf] = MFMA16(qf[1][ks], kf, S[1][nf]);
      }
    }

    // online softmax (row = lg*4 + r within 16-row fragment; 16-lane reduce)
#pragma unroll
    for (int mf = 0; mf < 2; ++mf) {
#pragma unroll
      for (int r = 0; r < 4; ++r) {
        float mx = S[mf][0][r];
#pragma unroll
        for (int nf = 1; nf < 8; ++nf) mx = fmaxf(mx, S[mf][nf][r]);
        mx = fmaxf(mx, __shfl_xor(mx, 1));
        mx = fmaxf(mx, __shfl_xor(mx, 2));
        mx = fmaxf(mx, __shfl_xor(mx, 4));
        mx = fmaxf(mx, __shfl_xor(mx, 8));
        float nm = fmaxf(runmax[mf][r], mx);
        float rf = __expf(runmax[mf][r] - nm);
        float rs = 0.f;
#pragma unroll
        for (int nf = 0; nf < 8; ++nf) {
          float p = __expf(S[mf][nf][r] - nm);
          S[mf][nf][r] = p;
          rs += p;
        }
        rs += __shfl_xor(rs, 1);
        rs += __shfl_xor(rs, 2);
        rs += __shfl_xor(rs, 4);
        rs += __shfl_xor(rs, 8);
        runsum[mf][r] = runsum[mf][r] * rf + rs;
        runmax[mf][r] = nm;
#pragma unroll
        for (int vn = 0; vn < 4; ++vn) O[mf][vn][r] *= rf;
      }
    }

    // P (C-layout) -> LDS -> A-layout fragments.  Wave-private; DS in-order.
#pragma unroll
    for (int mf = 0; mf < 2; ++mf)
#pragma unroll
      for (int nf = 0; nf < 8; ++nf)
#pragma unroll
        for (int r = 0; r < 4; ++r)
          u.Ps[wv][mf * 16 + lg * 4 + r][nf * 16 + lr] = (bf16)S[mf][nf][r];

#pragma unroll
    for (int ks = 0; ks < 4; ++ks) {
      bf16x8 pf0 = *(const bf16x8*)(&u.Ps[wv][lr][ks * 32 + lg * 8]);
      bf16x8 pf1 = *(const bf16x8*)(&u.Ps[wv][16 + lr][ks * 32 + lg * 8]);
#pragma unroll
      for (int vn = 0; vn < 4; ++vn) {
        bf16x8 vf = *(const bf16x8*)(&VTs[vn * 16 + lr][ks * 32 + lg * 8]);
        O[0][vn] = MFMA16(pf0, vf, O[0][vn]);
        O[1][vn] = MFMA16(pf1, vf, O[1][vn]);
      }
    }
  }

#pragma unroll
  for (int mf = 0; mf < 2; ++mf)
#pragma unroll
    for (int vn = 0; vn < 4; ++vn)
#pragma unroll
      for (int r = 0; r < 4; ++r) {
        int tok = q0 + wv * 32 + mf * 16 + lg * 4 + r;
        int d = vn * 16 + lr;
        float o = O[mf][vn][r] / runsum[mf][r];
        ATT[((size_t)bp * 384 + tok) * 768 + h * 64 + d] = (bf16)o;
      }
}

// ---------------------------------------------------------------------------
// Kernel 3: output projection. 256x256 tile, BK=64, f32 out + bias.
// ---------------------------------------------------------------------------
__global__ __launch_bounds__(512, 2) void proj_kernel(
    const bf16* __restrict__ A, const bf16* __restrict__ W,
    const float* __restrict__ bias, float* __restrict__ out)
{
  __shared__ bf16 As[2][256][64];
  __shared__ bf16 Bs[2][256][64];
  int bid = blockIdx.x;                    // 288 blocks
  int swz = (bid & 7) * 36 + (bid >> 3);   // 288 = 8*36
  const int nt = swz % 3, mt = swz / 3;
  const int m0 = mt * 256, n0 = nt * 256;
  const int tid = threadIdx.x;
  const int lane = tid & 63;
  const int wv = tid >> 6;
  const int wm = wv >> 2, wn = wv & 3;
  const int lr = lane & 15, lg = lane >> 4;

  const bf16* Ap = A + (size_t)m0 * 768;
  const bf16* Wp = W + (size_t)n0 * 768;

  f32x4 acc[8][4] = {};

  stage_tile64(Ap, &As[0][0][0], tid, wv);
  stage_tile64(Wp, &Bs[0][0][0], tid, wv);
  __syncthreads();

  for (int t = 0; t < 12; ++t) {
    if (t + 1 < 12) {
      stage_tile64(Ap + (t + 1) * 64, &As[(t + 1) & 1][0][0], tid, wv);
      stage_tile64(Wp + (t + 1) * 64, &Bs[(t + 1) & 1][0][0], tid, wv);
    }
    const bf16* Ab = &As[t & 1][0][0];
    const bf16* Bb = &Bs[t & 1][0][0];
    bf16x8 bfrag[4][2];
#pragma unroll
    for (int nf = 0; nf < 4; ++nf)
#pragma unroll
      for (int ks = 0; ks < 2; ++ks)
        bfrag[nf][ks] = frag64(Bb, wn * 64 + nf * 16 + lr, ks, lg);
#pragma unroll
    for (int mq = 0; mq < 4; ++mq) {
      bf16x8 af[2][2];
#pragma unroll
      for (int i = 0; i < 2; ++i)
#pragma unroll
        for (int ks = 0; ks < 2; ++ks)
          af[i][ks] = frag64(Ab, wm * 128 + (mq * 2 + i) * 16 + lr, ks, lg);
#pragma unroll
      for (int i = 0; i < 2; ++i)
#pragma unroll
        for (int nf = 0; nf < 4; ++nf)
#pragma unroll
          for (int ks = 0; ks < 2; ++ks)
            acc[mq * 2 + i][nf] = MFMA16(af[i][ks], bfrag[nf][ks], acc[mq * 2 + i][nf]);
    }
    __syncthreads();
  }

#pragma unroll
  for (int mf = 0; mf < 8; ++mf)
#pragma unroll
    for (int nf = 0; nf < 4; ++nf)
#pragma unroll
      for (int r = 0; r < 4; ++r) {
        int m = m0 + wm * 128 + mf * 16 + lg * 4 + r;
        int n = n0 + wn * 64 + nf * 16 + lr;
        out[(size_t)m * 768 + n] = acc[mf][nf][r] + bias[n];
      }
}

// ---------------------------------------------------------------------------
extern "C" void kernel_launch(void* const* d_in, const int* in_sizes, int n_in,
                              void* d_out, int out_size, void* d_ws, size_t ws_size,
                              hipStream_t stream) {
  (void)in_sizes; (void)n_in; (void)out_size; (void)ws_size;
  const float* xv     = (const float*)d_in[0];
  const float* xi     = (const float*)d_in[1];
  const float* qkv_w  = (const float*)d_in[2];
  const float* proj_w = (const float*)d_in[3];
  const float* proj_b = (const float*)d_in[4];
  float* out = (float*)d_out;

  // bf16 scratch inside d_out (75.5 MB): Xb [24576][768] then Wq [2304][768].
  bf16* Xb = (bf16*)d_out;
  bf16* Wq = Xb + (size_t)18874368;

  // ws: Q | K | V | ATT, each 18874368 bf16 (~36 MB) = 151 MB total.
  const size_t SZ = (size_t)64 * 12 * 384 * 64;
  bf16* Q   = (bf16*)d_ws;
  bf16* K   = Q + SZ;
  bf16* V   = K + SZ;
  bf16* ATT = V + SZ;
  bf16* Wp  = Q;                 // proj_w bf16, reuses Q region after attn

  convert1_kernel<<<2048, 256, 0, stream>>>(xv, xi, qkv_w, Xb);
  qkv_kernel<<<864, 512, 0, stream>>>(Xb, Wq, Q, K, V);
  attn_kernel<<<64 * 12 * 3, 256, 0, stream>>>(Q, K, V, ATT);
  convert2_kernel<<<288, 256, 0, stream>>>(proj_w, Wp);
  proj_kernel<<<288, 512, 0, stream>>>(ATT, Wp, proj_b, out);
}